// Round 6
// baseline (7035.563 us; speedup 1.0000x reference)
//
#include <hip/hip_runtime.h>

// ODE_Vanilla scan: B=128, T=256, I=256, H=1024, C=10, fp32 throughout.
//   phase1: v = a*h - relu(h@Wh + XW[t])   (XW = X@Wx + b precomputed)
//   phase2: u = v@Wh^T; grad = a*v - (phi>0)*u; h -= LR*grad
//   out[b,t,:] = h_{t+1}... wait: out uses h AFTER the update at step t.
// R8: tail-ectomy. Phase2's FC epilogue (atomics + extra sync + scalar fc_w
// reads) removed; FC for step t-1 runs in 16 DEDICATED blocks appended to
// phase1's grid (read h from global, write out directly with fc_b — no
// atomics, no out-init, no straggler coupling). Last step via k_fc_last.
// Core GEMM structure = R7 (direct-global rows, value-split reduce).

constexpr int Bsz = 128, Tn = 256, In = 256, Hn = 1024, Cn = 10;
constexpr float LR = 0.001f;

__global__ __launch_bounds__(256) void k_transpose(const float* __restrict__ W,
                                                   float* __restrict__ WT) {
  __shared__ float tile[32][33];
  const int bx = blockIdx.x * 32, by = blockIdx.y * 32;
  const int tx = threadIdx.x & 31, ty = threadIdx.x >> 5;
#pragma unroll
  for (int dy = 0; dy < 32; dy += 8)
    tile[ty + dy][tx] = W[(size_t)(by + ty + dy) * Hn + bx + tx];
  __syncthreads();
#pragma unroll
  for (int dy = 0; dy < 32; dy += 8)
    WT[(size_t)(bx + ty + dy) * Hn + by + tx] = tile[tx][ty + dy];
}

__global__ __launch_bounds__(256) void k_init(float* __restrict__ h_cur,
                                              const float* __restrict__ hidden) {
  const int i = blockIdx.x * 256 + threadIdx.x;  // grid 512 covers 128*1024
  h_cur[i] = hidden[i];
}

__device__ __forceinline__ void fma4(float4& a, float s, const float4& w) {
  a.x = fmaf(s, w.x, a.x);
  a.y = fmaf(s, w.y, a.y);
  a.z = fmaf(s, w.z, a.z);
  a.w = fmaf(s, w.w, a.w);
}

__device__ __forceinline__ float4 shfl4(float4 v, int m) {
  v.x = __shfl_xor(v.x, m, 64);
  v.y = __shfl_xor(v.y, m, 64);
  v.z = __shfl_xor(v.z, m, 64);
  v.w = __shfl_xor(v.w, m, 64);
  return v;
}

__device__ __forceinline__ float4 add4(float4 a, float4 b) {
  return make_float4(a.x + b.x, a.y + b.y, a.z + b.z, a.w + b.w);
}

// XW[t][b][n] = sum_k X[b][t][k]*Wx[k][n] + bias[n].
__global__ __launch_bounds__(256) void k_xw(const float* __restrict__ X,
                                            const float* __restrict__ Wx,
                                            const float* __restrict__ bias,
                                            float* __restrict__ xw) {
  const int nt = blockIdx.x & 15, mt = blockIdx.x >> 4;
  const int t = mt >> 1, b0 = (mt & 1) * 64;
  const int cl = threadIdx.x & 15, rg = threadIdx.x >> 4;
  const int col = nt * 64 + cl * 4;
  const int row = b0 + rg * 4;
  float4 acc0 = {0, 0, 0, 0}, acc1 = {0, 0, 0, 0}, acc2 = {0, 0, 0, 0},
         acc3 = {0, 0, 0, 0};
  const size_t xstride = (size_t)Tn * In;
  const float* xp = X + ((size_t)row * Tn + t) * In;
  const float* wp = Wx + col;
#pragma unroll 2
  for (int k = 0; k < In; k += 4) {
    const float4 x0 = *(const float4*)(xp + k);
    const float4 x1 = *(const float4*)(xp + xstride + k);
    const float4 x2 = *(const float4*)(xp + 2 * xstride + k);
    const float4 x3 = *(const float4*)(xp + 3 * xstride + k);
    const float4 w0 = *(const float4*)(wp + (size_t)k * Hn);
    const float4 w1 = *(const float4*)(wp + (size_t)(k + 1) * Hn);
    const float4 w2 = *(const float4*)(wp + (size_t)(k + 2) * Hn);
    const float4 w3 = *(const float4*)(wp + (size_t)(k + 3) * Hn);
    fma4(acc0, x0.x, w0); fma4(acc0, x0.y, w1); fma4(acc0, x0.z, w2); fma4(acc0, x0.w, w3);
    fma4(acc1, x1.x, w0); fma4(acc1, x1.y, w1); fma4(acc1, x1.z, w2); fma4(acc1, x1.w, w3);
    fma4(acc2, x2.x, w0); fma4(acc2, x2.y, w1); fma4(acc2, x2.z, w2); fma4(acc2, x2.w, w3);
    fma4(acc3, x3.x, w0); fma4(acc3, x3.y, w1); fma4(acc3, x3.z, w2); fma4(acc3, x3.w, w3);
  }
  const float4 b4 = *(const float4*)(bias + col);
  float4 o[4] = {acc0, acc1, acc2, acc3};
#pragma unroll
  for (int i = 0; i < 4; i++) {
    float4 v = o[i];
    v.x += b4.x; v.y += b4.y; v.z += b4.z; v.w += b4.w;
    *(float4*)(xw + ((size_t)t * Bsz + row + i) * Hn + col) = v;
  }
}

// 8-rows x 16-cols x K=1024 panel GEMM; thread = c4(4) x kk(64). Rows read
// straight from global (L2-hot; 4 c4-lanes share each address -> broadcast).
__device__ __forceinline__ void gemm8g(const float* __restrict__ rows,
                                       const float* __restrict__ W, int kk,
                                       int col, float4 acc[8]) {
#pragma unroll
  for (int q = 0; q < 4; q++) {
    const int k = 4 * kk + 256 * q;
    const float* Wp = W + (size_t)k * Hn + col;
    const float4 w0 = *(const float4*)(Wp);
    const float4 w1 = *(const float4*)(Wp + Hn);
    const float4 w2 = *(const float4*)(Wp + 2 * Hn);
    const float4 w3 = *(const float4*)(Wp + 3 * Hn);
#pragma unroll
    for (int r = 0; r < 8; r++) {
      const float4 h4 = *(const float4*)(rows + (size_t)r * Hn + k);
      fma4(acc[r], h4.x, w0);
      fma4(acc[r], h4.y, w1);
      fma4(acc[r], h4.z, w2);
      fma4(acc[r], h4.w, w3);
    }
  }
}

// Value-splitting reduce over ks lane bits 2..5 (validated in R5/R7): 30 shfl.
// Lane ends owning float2 at (r_own, 4*c4 + 2*u4); writes part[wv].
__device__ __forceinline__ void reduce_vs(float4 acc[8], int c4, int ksw,
                                          int wv, float (*part)[8][16]) {
  const bool u1 = ksw & 1;
#pragma unroll
  for (int i = 0; i < 4; i++) {
    const float4 snd = u1 ? acc[i] : acc[i + 4];
    const float4 kp = u1 ? acc[i + 4] : acc[i];
    acc[i] = add4(kp, shfl4(snd, 4));
  }
  const bool u2 = ksw & 2;
#pragma unroll
  for (int i = 0; i < 2; i++) {
    const float4 snd = u2 ? acc[i] : acc[i + 2];
    const float4 kp = u2 ? acc[i + 2] : acc[i];
    acc[i] = add4(kp, shfl4(snd, 8));
  }
  const bool u3 = ksw & 4;
  {
    const float4 snd = u3 ? acc[0] : acc[1];
    const float4 kp = u3 ? acc[1] : acc[0];
    acc[0] = add4(kp, shfl4(snd, 16));
  }
  const bool u4 = ksw & 8;
  float sx = u4 ? acc[0].x : acc[0].z;
  float sy = u4 ? acc[0].y : acc[0].w;
  const float kx = u4 ? acc[0].z : acc[0].x;
  const float ky = u4 ? acc[0].w : acc[0].y;
  sx = __shfl_xor(sx, 32, 64);
  sy = __shfl_xor(sy, 32, 64);
  const int r_own = ((ksw & 1) << 2) | (ksw & 2) | ((ksw >> 2) & 1);
  const int c_own = 4 * c4 + (u4 ? 2 : 0);
  *(float2*)&part[wv][r_own][c_own] = make_float2(kx + sx, ky + sy);
}

// grid 1040 = 1024 GEMM blocks (rt(16) x ct(64)) + 16 FC blocks.
// GEMM thread = c4(4) x kk(64). FC blocks compute out[:, t-1, :].
template <int PRE>
__global__ __launch_bounds__(256, 4) void k_phase1(
    const float* __restrict__ h, const float* __restrict__ X,
    const float* __restrict__ Wh, const float* __restrict__ Wx,
    const float* __restrict__ bias, const float* __restrict__ alpha,
    const float* __restrict__ xw, const float* __restrict__ fc_w,
    const float* __restrict__ fc_b, float* __restrict__ out,
    float* __restrict__ v_out, int t) {
  const int tid = threadIdx.x;
  if (blockIdx.x >= 1024) {  // FC block: out[:, t-1, :] = h@fc_w + fc_b
    if (t == 0) return;
    const int r0b = (blockIdx.x - 1024) * 8;
    const int r = tid >> 5, l = tid & 31;
    const int c = l & 15, half = l >> 4;
    float s = 0.f;
    if (c < Cn) {
      const float* hp = h + (size_t)(r0b + r) * Hn + half * 512;
#pragma unroll 4
      for (int k = 0; k < 512; k += 4) {
        const float4 h4 = *(const float4*)(hp + k);
        const float* fw = fc_w + (size_t)(half * 512 + k) * Cn + c;
        s = fmaf(h4.x, fw[0], s);
        s = fmaf(h4.y, fw[Cn], s);
        s = fmaf(h4.z, fw[2 * Cn], s);
        s = fmaf(h4.w, fw[3 * Cn], s);
      }
    }
    s += __shfl_xor(s, 16, 64);
    if (c < Cn && half == 0)
      out[((size_t)(r0b + r) * Tn + (t - 1)) * Cn + c] = s + fc_b[c];
    return;
  }
  __shared__ float part[4][8][16];
  const int ct = blockIdx.x & 63, rt = blockIdx.x >> 6;
  const int c0 = ct * 16, r0 = rt * 8;
  const int c4 = tid & 3, kk = tid >> 2;
  const int col = c0 + 4 * c4;
  const int wv = tid >> 6, ksw = (tid & 63) >> 2;
  const float* hbase = h + (size_t)r0 * Hn;

  float4 acc[8];
#pragma unroll
  for (int r = 0; r < 8; r++) acc[r] = {0.f, 0.f, 0.f, 0.f};
  gemm8g(hbase, Wh, kk, col, acc);
  if (!PRE) {  // x@Wx inline: thread kk owns Wx row-quad 4kk (I=256=64*4)
    const int kx = 4 * kk;
    const float* Wp = Wx + (size_t)kx * Hn + col;
    const float4 w0 = *(const float4*)(Wp);
    const float4 w1 = *(const float4*)(Wp + Hn);
    const float4 w2 = *(const float4*)(Wp + 2 * Hn);
    const float4 w3 = *(const float4*)(Wp + 3 * Hn);
#pragma unroll
    for (int r = 0; r < 8; r++) {
      const float4 x4 =
          *(const float4*)(X + ((size_t)(r0 + r) * Tn + t) * In + kx);
      fma4(acc[r], x4.x, w0);
      fma4(acc[r], x4.y, w1);
      fma4(acc[r], x4.z, w2);
      fma4(acc[r], x4.w, w3);
    }
  }
  reduce_vs(acc, c4, ksw, wv, part);
  __syncthreads();
  if (tid < 128) {
    const int r = tid >> 4, c = tid & 15;
    const float u =
        part[0][r][c] + part[1][r][c] + part[2][r][c] + part[3][r][c];
    const float a1 =
        PRE ? xw[((size_t)t * Bsz + r0 + r) * Hn + c0 + c] : bias[c0 + c];
    const float av = alpha[0];
    const float hv = hbase[(size_t)r * Hn + c0 + c];
    v_out[(size_t)(r0 + r) * Hn + c0 + c] = av * hv - fmaxf(u + a1, 0.f);
  }
}

__global__ __launch_bounds__(256, 4) void k_phase2(
    float* __restrict__ h, const float* __restrict__ v_in,
    const float* __restrict__ WT, const float* __restrict__ alpha,
    float* __restrict__ hfin, int last) {
  __shared__ float part[4][8][16];
  const int ct = blockIdx.x & 63, rt = blockIdx.x >> 6;
  const int c0 = ct * 16, r0 = rt * 8;
  const int tid = threadIdx.x;
  const int c4 = tid & 3, kk = tid >> 2;
  const int col = c0 + 4 * c4;
  const int wv = tid >> 6, ksw = (tid & 63) >> 2;
  const float* vbase = v_in + (size_t)r0 * Hn;

  float4 acc[8];
#pragma unroll
  for (int r = 0; r < 8; r++) acc[r] = {0.f, 0.f, 0.f, 0.f};
  gemm8g(vbase, WT, kk, col, acc);
  reduce_vs(acc, c4, ksw, wv, part);
  __syncthreads();
  if (tid < 128) {
    const int r = tid >> 4, c = tid & 15;
    const float u =
        part[0][r][c] + part[1][r][c] + part[2][r][c] + part[3][r][c];
    const float av = alpha[0];
    const size_t hoff = (size_t)(r0 + r) * Hn + c0 + c;
    const float vv = vbase[(size_t)r * Hn + c0 + c];
    const float hv = h[hoff];
    // phi = a*h - v; grad = a*v - (phi>0)*u; hn = h - LR*grad
    const float hn = hv - LR * (av * vv - ((av * hv - vv) > 0.f ? u : 0.f));
    h[hoff] = hn;
    if (last) hfin[hoff] = hn;
  }
}

// FC for the final timestep: out[:, T-1, :] = h_final @ fc_w + fc_b. grid 16.
__global__ __launch_bounds__(256) void k_fc_last(const float* __restrict__ h,
                                                 const float* __restrict__ fc_w,
                                                 const float* __restrict__ fc_b,
                                                 float* __restrict__ out) {
  const int r0 = blockIdx.x * 8;
  const int r = threadIdx.x >> 5, l = threadIdx.x & 31;
  const int c = l & 15, half = l >> 4;
  float s = 0.f;
  if (c < Cn) {
    const float* hp = h + (size_t)(r0 + r) * Hn + half * 512;
#pragma unroll 4
    for (int k = 0; k < 512; k += 4) {
      const float4 h4 = *(const float4*)(hp + k);
      const float* fw = fc_w + (size_t)(half * 512 + k) * Cn + c;
      s = fmaf(h4.x, fw[0], s);
      s = fmaf(h4.y, fw[Cn], s);
      s = fmaf(h4.z, fw[2 * Cn], s);
      s = fmaf(h4.w, fw[3 * Cn], s);
    }
  }
  s += __shfl_xor(s, 16, 64);
  if (c < Cn && half == 0)
    out[((size_t)(r0 + r) * Tn + (Tn - 1)) * Cn + c] = s + fc_b[c];
}

extern "C" void kernel_launch(void* const* d_in, const int* in_sizes, int n_in,
                              void* d_out, int out_size, void* d_ws, size_t ws_size,
                              hipStream_t stream) {
  const float* X      = (const float*)d_in[0];
  const float* hidden = (const float*)d_in[1];
  const float* alpha  = (const float*)d_in[2];
  const float* bias   = (const float*)d_in[3];
  const float* Wh     = (const float*)d_in[4];
  const float* Wx     = (const float*)d_in[5];
  const float* fc_w   = (const float*)d_in[6];
  const float* fc_b   = (const float*)d_in[7];
  float* out  = (float*)d_out;
  float* hfin = out + (size_t)Bsz * Tn * Cn;

  char* ws = (char*)d_ws;
  float* WhT   = (float*)ws;                        // 4 MB
  float* h_cur = WhT + (size_t)Hn * Hn;
  float* v_buf = h_cur + (size_t)Bsz * Hn;
  float* XW    = v_buf + (size_t)Bsz * Hn;          // 134 MB, [t][b][n]
  const size_t need =
      ((size_t)Hn * Hn + 2 * (size_t)Bsz * Hn + (size_t)Bsz * Tn * Hn) *
      sizeof(float);
  const bool pre = ws_size >= need;

  k_transpose<<<dim3(32, 32), 256, 0, stream>>>(Wh, WhT);
  k_init<<<512, 256, 0, stream>>>(h_cur, hidden);
  if (pre) k_xw<<<8192, 256, 0, stream>>>(X, Wx, bias, XW);
  for (int t = 0; t < Tn; t++) {
    if (pre)
      k_phase1<1><<<1040, 256, 0, stream>>>(h_cur, X, Wh, Wx, bias, alpha, XW,
                                            fc_w, fc_b, out, v_buf, t);
    else
      k_phase1<0><<<1040, 256, 0, stream>>>(h_cur, X, Wh, Wx, bias, alpha, XW,
                                            fc_w, fc_b, out, v_buf, t);
    k_phase2<<<1024, 256, 0, stream>>>(h_cur, v_buf, WhT, alpha, hfin,
                                       t == Tn - 1);
  }
  k_fc_last<<<16, 256, 0, stream>>>(h_cur, fc_w, fc_b, out);
}